// Round 16
// baseline (55.787 us; speedup 1.0000x reference)
//
#include <hip/hip_runtime.h>
#include <hip/hip_bf16.h>
#include <stdint.h>

// Problem constants
#define BB 16
#define NPTS 100000
#define NBOX 64
#define KTOP 2048
#define THRF 0.2f            // (float)(8*0.01*2.5)
// band around 0.2^2 for exact-path fallback; fast path error bound ~5e-6
#define C_LO 0.039984f
#define C_HI 0.040016f

#define SLICES 16
#define SLICE_SPAN 6272      // 15*6272 + 5920 = 100000
#define SCAP 512             // per-slice cap (expected ~143 +/- 12)
#define LIST_CAP 4096        // per-batch cap (expected ~2278 +/- 47)
#define CUT 0xC0000000u      // fmap(2.0f)

// Workspace (uint32 words). No zeroing needed.
#define CAND_OFF 0                            // BB*SLICES*SCAP
#define CNT_OFF  (BB * SLICES * SCAP)         // BB*SLICES
#define STATE_OFF (CNT_OFF + BB * SLICES)     // BB*2 {T_bits, Istar}

__device__ __forceinline__ uint32_t fmap(float f) {
    uint32_t b = __float_as_uint(f);
    return (b & 0x80000000u) ? ~b : (b | 0x80000000u);
}

// ---------- K1: full-machine candidate filter (scores >= 2.0) ----------
__global__ __launch_bounds__(256) void cand_k(const float* __restrict__ scores,
                                              uint32_t* __restrict__ ws) {
    __shared__ uint32_t buf[SCAP];
    __shared__ uint32_t lcnt;
    const int b = blockIdx.y, sl = blockIdx.x, tid = threadIdx.x;
    if (tid == 0) lcnt = 0;
    __syncthreads();
    const int start = sl * SLICE_SPAN;
    const int nf4 = min(SLICE_SPAN, NPTS - start) >> 2;
    const float4* sc4 = reinterpret_cast<const float4*>(scores + (size_t)b * NPTS + start);
    for (int i4 = tid; i4 < nf4; i4 += 256) {
        const float4 v = sc4[i4];
        const uint32_t u[4] = {fmap(v.x), fmap(v.y), fmap(v.z), fmap(v.w)};
#pragma unroll
        for (int j = 0; j < 4; ++j) {
            if (u[j] >= CUT) {
                const uint32_t pos = atomicAdd(&lcnt, 1u);
                if (pos < SCAP) buf[pos] = u[j];
            }
        }
    }
    __syncthreads();
    const uint32_t c = lcnt;
    uint32_t* dst = ws + CAND_OFF + ((size_t)(b * SLICES + sl)) * SCAP;
    const uint32_t cw = c < SCAP ? c : SCAP;
    for (uint32_t i = tid; i < cw; i += 256) dst[i] = buf[i];
    if (tid == 0) ws[CNT_OFF + b * SLICES + sl] = c;
}

// 256-thread suffix-sum pick
__device__ __forceinline__ void pick256(const uint32_t* __restrict__ hist,
                                        uint32_t* __restrict__ excl,
                                        int tid, int lane, uint32_t target,
                                        uint32_t* sBin, uint32_t* sKrem,
                                        uint32_t* sE, uint32_t* sTot, int wantE) {
    __syncthreads();
    if (tid < 64) {
        const uint32_t v0 = hist[4*tid], v1 = hist[4*tid+1], v2 = hist[4*tid+2], v3 = hist[4*tid+3];
        const uint32_t lt = v0 + v1 + v2 + v3;
        uint32_t x = lt;
#pragma unroll
        for (int off = 1; off < 64; off <<= 1) {
            const uint32_t y = __shfl_up(x, off);
            if (lane >= off) x += y;
        }
        const uint32_t ex = x - lt;
        excl[4*tid] = ex; excl[4*tid+1] = ex + v0;
        excl[4*tid+2] = ex + v0 + v1; excl[4*tid+3] = ex + v0 + v1 + v2;
        if (tid == 63) *sTot = x;
    }
    __syncthreads();
    {
        const uint32_t total = *sTot, lim = total - target;
        const uint32_t pe = excl[tid];
        const uint32_t pe1 = (tid == 255) ? total : excl[tid + 1];
        if (pe <= lim && pe1 > lim) {
            *sBin = (uint32_t)tid;
            *sKrem = target - (total - pe1);
            if (wantE) *sE = pe1 - pe;
        }
    }
    __syncthreads();
}

// ---------- K2: per-batch radix select ----------
__global__ __launch_bounds__(256) void selfin_k(const float* __restrict__ scores,
                                                const float* __restrict__ ctrs,
                                                uint32_t* __restrict__ ws) {
    const int b = blockIdx.x, tid = threadIdx.x, w = tid >> 6, lane = tid & 63;
    __shared__ uint32_t list[LIST_CAP];
    __shared__ uint32_t h4[4][257];
    __shared__ uint32_t hist[256], excl[256];
    __shared__ uint32_t scnt[SLICES], soff[SLICES];
    __shared__ uint32_t wcnt[4];
    __shared__ uint32_t sBin, sKrem, sE, sTot, sIstar, sRun, sSpec, sUni, lcnt;
    const float* sc = scores + (size_t)b * NPTS;
    if (tid < SLICES) scnt[tid] = ws[CNT_OFF + b * SLICES + tid];
    __syncthreads();
    if (tid == 0) {
        uint32_t tot = 0; bool ok = true;
        for (int s = 0; s < SLICES; ++s) {
            soff[s] = tot;
            const uint32_t c = scnt[s];
            if (c > SCAP) ok = false;
            tot += c;
        }
        sTot = tot;
        sSpec = (ok && tot >= KTOP && tot <= LIST_CAP) ? 1u : 0u;
        sKrem = KTOP; sIstar = NPTS; lcnt = 0; sUni = 1u;
    }
    __syncthreads();
    uint32_t cnt, prefix = 0u;
    int shift0;
    if (sSpec) {
        cnt = sTot;
#pragma unroll 2
        for (int s = 0; s < SLICES; ++s) {
            const uint32_t c = scnt[s], o = soff[s];
            const uint32_t* src = ws + CAND_OFF + ((size_t)(b * SLICES + s)) * SCAP;
            for (uint32_t i = tid; i < c; i += 256) list[o + i] = src[i];
        }
        __syncthreads();
        const uint32_t b0 = list[0] >> 24;
        bool uni = true;
        for (uint32_t i = tid; i < cnt; i += 256) uni &= ((list[i] >> 24) == b0);
        if (!uni) atomicAnd(&sUni, 0u);
        __syncthreads();
        if (sUni) { prefix = b0 << 24; shift0 = 16; }
        else      { prefix = 0u;       shift0 = 24; }
    } else {
        for (int i = tid; i < 4 * 257; i += 256) (&h4[0][0])[i] = 0;
        __syncthreads();
        const float4* sc4 = reinterpret_cast<const float4*>(sc);
        for (int i4 = tid; i4 < NPTS / 4; i4 += 256) {
            const float4 v = sc4[i4];
            atomicAdd(&h4[w][fmap(v.x) >> 24], 1u);
            atomicAdd(&h4[w][fmap(v.y) >> 24], 1u);
            atomicAdd(&h4[w][fmap(v.z) >> 24], 1u);
            atomicAdd(&h4[w][fmap(v.w) >> 24], 1u);
        }
        __syncthreads();
        hist[tid] = h4[0][tid] + h4[1][tid] + h4[2][tid] + h4[3][tid];
        pick256(hist, excl, tid, lane, KTOP, &sBin, &sKrem, &sE, &sTot, 0);
        const uint32_t beta = sBin;
        for (int i4 = tid; i4 < NPTS / 4; i4 += 256) {
            const float4 v = sc4[i4];
            const uint32_t u[4] = {fmap(v.x), fmap(v.y), fmap(v.z), fmap(v.w)};
#pragma unroll
            for (int j = 0; j < 4; ++j) {
                if ((u[j] >> 24) == beta) {
                    const uint32_t pos = atomicAdd(&lcnt, 1u);
                    if (pos < LIST_CAP) list[pos] = u[j];
                }
            }
        }
        __syncthreads();
        cnt = lcnt < LIST_CAP ? lcnt : LIST_CAP;
        prefix = beta << 24; shift0 = 16;
    }
#pragma unroll 1
    for (int shift = shift0; shift >= 0; shift -= 8) {
        for (int i = tid; i < 4 * 257; i += 256) (&h4[0][0])[i] = 0;
        __syncthreads();
        const uint32_t hi8 = (shift < 24) ? (prefix >> (shift + 8)) : 0u;
        uint32_t* mh = h4[lane & 3];
        for (uint32_t i = tid; i < cnt; i += 256) {
            const uint32_t uu = list[i];
            const bool m = (shift == 24) || ((uu >> (shift + 8)) == hi8);
            if (m) atomicAdd(&mh[(uu >> shift) & 255u], 1u);
        }
        __syncthreads();
        hist[tid] = h4[0][tid] + h4[1][tid] + h4[2][tid] + h4[3][tid];
        const uint32_t target = sKrem;
        pick256(hist, excl, tid, lane, target, &sBin, &sKrem, &sE, &sTot, shift == 0 ? 1 : 0);
        prefix |= sBin << shift;
    }
    const uint32_t R = sKrem, E = sE;
    const uint32_t tbits = (prefix & 0x80000000u) ? (prefix & 0x7fffffffu) : ~prefix;
    if (E != R) {
        const float T = __uint_as_float(tbits);
        if (tid == 0) sRun = 0;
        __syncthreads();
        for (int base = 0; base < NPTS; base += 256) {
            const uint32_t r0 = sRun;
            if (r0 > R) break;
            const int i = base + tid;
            const bool eq = (i < NPTS) && (sc[i] == T);
            const unsigned long long mask = __ballot(eq);
            if (lane == 0) wcnt[w] = (uint32_t)__popcll(mask);
            __syncthreads();
            uint32_t before = 0, total = 0;
#pragma unroll
            for (int ww = 0; ww < 4; ++ww) {
                const uint32_t c = wcnt[ww];
                if (ww < w) before += c;
                total += c;
            }
            if (eq) {
                const uint32_t rank = r0 + before + (uint32_t)__popcll(mask & ((1ull << lane) - 1ull));
                if (rank == R) sIstar = (uint32_t)i;
            }
            __syncthreads();
            if (tid == 0) sRun = r0 + total;
            __syncthreads();
        }
        __syncthreads();
    }
    if (tid == 0) {
        ws[STATE_OFF + b * 2] = tbits;
        ws[STATE_OFF + b * 2 + 1] = sIstar;
    }
}

// ---------- exact (numpy-bit-identical) gt check for one point ----------
__device__ __noinline__ bool exact_gt(float px, float py, float pz,
                                      const float* __restrict__ C) {
    bool hit = false;
#pragma unroll 1
    for (int k = 0; k < NBOX; ++k) {
        float dx = px - C[3 * k + 0];
        float dy = py - C[3 * k + 1];
        float dz = pz - C[3 * k + 2];
        float d2 = __fadd_rn(__fadd_rn(__fmul_rn(dx, dx), __fmul_rn(dy, dy)),
                             __fmul_rn(dz, dz));
        if (__fsqrt_rn(d2) < THRF) hit = true;
    }
    return hit;
}

// ---------- K3: body, 8 points/thread, s_load-able box constants ----------
#define PPT 8
__global__ __launch_bounds__(256) void main_k(const float* __restrict__ scores,
                                              const float* __restrict__ points,
                                              const float* __restrict__ ctrs,
                                              const uint32_t* __restrict__ ws,
                                              float* __restrict__ out) {
    const int b = blockIdx.y;
    const int i0 = (blockIdx.x * 256 + threadIdx.x) * PPT;
    if (i0 >= NPTS) return;  // NPTS % 8 == 0: threads are fully valid or fully invalid

    const float T = __uint_as_float(ws[STATE_OFF + b * 2]);
    const uint32_t Istar = ws[STATE_OFF + b * 2 + 1];
    const float* __restrict__ C = ctrs + (size_t)b * NBOX * 3;  // clean, uniform -> s_load

    // load 8 points = 24 floats = 6 float4 (i0*3 % 4 == 0: aligned)
    const float4* P4 = reinterpret_cast<const float4*>(points + ((size_t)b * NPTS + i0) * 3);
    float4 q[6];
#pragma unroll
    for (int j = 0; j < 6; ++j) q[j] = P4[j];
    const float* pf = reinterpret_cast<const float*>(q);
    float qx[PPT], qy[PPT], qz[PPT], pp[PPT], m2[PPT];
#pragma unroll
    for (int j = 0; j < PPT; ++j) {
        const float px = pf[3*j], py = pf[3*j+1], pz = pf[3*j+2];
        qx[j] = -2.0f * px; qy[j] = -2.0f * py; qz[j] = -2.0f * pz;
        pp[j] = fmaf(px, px, fmaf(py, py, pz * pz));
        m2[j] = 1e30f;
    }

    // 64 boxes: per box 3 uniform VALU (cc) + 8x4 per-point VALU
#pragma unroll 4
    for (int k = 0; k < NBOX; ++k) {
        const float cx = C[3*k], cy = C[3*k+1], cz = C[3*k+2];  // SGPR loads
        const float cc = fmaf(cx, cx, fmaf(cy, cy, cz * cz));
#pragma unroll
        for (int j = 0; j < PPT; ++j) {
            const float t = fmaf(cx, qx[j], fmaf(cy, qy[j], fmaf(cz, qz[j], cc)));
            m2[j] = fminf(m2[j], t);
        }
    }

    const float4* S4 = reinterpret_cast<const float4*>(scores + (size_t)b * NPTS + i0);
    float4 sv[2] = {S4[0], S4[1]};
    const float* s = reinterpret_cast<const float*>(sv);
    float pr[PPT], ls[PPT];
#pragma unroll
    for (int j = 0; j < PPT; ++j) {
        const float m = pp[j] + m2[j];
        bool gt;
        if (m < C_LO) gt = true;
        else if (m >= C_HI) gt = false;
        else gt = exact_gt(pf[3*j], pf[3*j+1], pf[3*j+2], C);  // rare boundary band
        const bool sm = (s[j] > T) || (s[j] == T && (uint32_t)(i0 + j) < Istar);
        pr[j] = (gt || sm) ? 1.0f : 0.0f;
        const float x = gt ? -s[j] : s[j];
        // fast softplus: tolerance is bf16-level (9.4e-2); hw exp/log err ~1e-6
        ls[j] = fmaxf(x, 0.0f) + __logf(1.0f + __expf(-fabsf(s[j])));
    }
    float4* o0 = reinterpret_cast<float4*>(out + (size_t)b * NPTS + i0);
    float4* o1 = reinterpret_cast<float4*>(out + (size_t)BB * NPTS + (size_t)b * NPTS + i0);
    o0[0] = make_float4(pr[0], pr[1], pr[2], pr[3]);
    o0[1] = make_float4(pr[4], pr[5], pr[6], pr[7]);
    o1[0] = make_float4(ls[0], ls[1], ls[2], ls[3]);
    o1[1] = make_float4(ls[4], ls[5], ls[6], ls[7]);
}

extern "C" void kernel_launch(void* const* d_in, const int* in_sizes, int n_in,
                              void* d_out, int out_size, void* d_ws, size_t ws_size,
                              hipStream_t stream) {
    const float* scores = (const float*)d_in[0];
    const float* points = (const float*)d_in[1];
    const float* ctrs   = (const float*)d_in[2];
    float* out = (float*)d_out;
    uint32_t* ws = (uint32_t*)d_ws;

    const dim3 gridC(SLICES, BB);   // 256 blocks
    cand_k<<<gridC, 256, 0, stream>>>(scores, ws);
    selfin_k<<<BB, 256, 0, stream>>>(scores, ctrs, ws);
    const dim3 gridP((NPTS / PPT + 255) / 256, BB);  // 49 x 16
    main_k<<<gridP, 256, 0, stream>>>(scores, points, ctrs, ws, out);
}

// Round 17
// 53.779 us; speedup vs baseline: 1.0373x; 1.0373x over previous
//
#include <hip/hip_runtime.h>
#include <hip/hip_bf16.h>
#include <stdint.h>

// Problem constants
#define BB 16
#define NPTS 100000
#define NBOX 64
#define KTOP 2048
#define THRF 0.2f            // (float)(8*0.01*2.5)
// band around 0.2^2 for exact-path fallback; fast path error bound ~5e-6
#define C_LO 0.039984f
#define C_HI 0.040016f

#define SLICES 16
#define SLICE_SPAN 6272      // 15*6272 + 5920 = 100000
#define SCAP 512             // per-slice cap (expected ~143 +/- 12)
#define LIST_CAP 4096        // per-batch cap (expected ~2278 +/- 47)
#define CUT 0xC0000000u      // fmap(2.0f)

// Workspace (uint32 words). No zeroing needed.
#define CAND_OFF 0                            // BB*SLICES*SCAP
#define CNT_OFF  (BB * SLICES * SCAP)         // BB*SLICES
#define STATE_OFF (CNT_OFF + BB * SLICES)     // BB*2 {T_bits, Istar}

__device__ __forceinline__ uint32_t fmap(float f) {
    uint32_t b = __float_as_uint(f);
    return (b & 0x80000000u) ? ~b : (b | 0x80000000u);
}

// ---------- K1: full-machine candidate filter (scores >= 2.0) ----------
__global__ __launch_bounds__(256) void cand_k(const float* __restrict__ scores,
                                              uint32_t* __restrict__ ws) {
    __shared__ uint32_t buf[SCAP];
    __shared__ uint32_t lcnt;
    const int b = blockIdx.y, sl = blockIdx.x, tid = threadIdx.x;
    if (tid == 0) lcnt = 0;
    __syncthreads();
    const int start = sl * SLICE_SPAN;
    const int nf4 = min(SLICE_SPAN, NPTS - start) >> 2;
    const float4* sc4 = reinterpret_cast<const float4*>(scores + (size_t)b * NPTS + start);
    for (int i4 = tid; i4 < nf4; i4 += 256) {
        const float4 v = sc4[i4];
        const uint32_t u[4] = {fmap(v.x), fmap(v.y), fmap(v.z), fmap(v.w)};
#pragma unroll
        for (int j = 0; j < 4; ++j) {
            if (u[j] >= CUT) {
                const uint32_t pos = atomicAdd(&lcnt, 1u);
                if (pos < SCAP) buf[pos] = u[j];
            }
        }
    }
    __syncthreads();
    const uint32_t c = lcnt;
    uint32_t* dst = ws + CAND_OFF + ((size_t)(b * SLICES + sl)) * SCAP;
    const uint32_t cw = c < SCAP ? c : SCAP;
    for (uint32_t i = tid; i < cw; i += 256) dst[i] = buf[i];
    if (tid == 0) ws[CNT_OFF + b * SLICES + sl] = c;
}

// 256-thread suffix-sum pick
__device__ __forceinline__ void pick256(const uint32_t* __restrict__ hist,
                                        uint32_t* __restrict__ excl,
                                        int tid, int lane, uint32_t target,
                                        uint32_t* sBin, uint32_t* sKrem,
                                        uint32_t* sE, uint32_t* sTot, int wantE) {
    __syncthreads();
    if (tid < 64) {
        const uint32_t v0 = hist[4*tid], v1 = hist[4*tid+1], v2 = hist[4*tid+2], v3 = hist[4*tid+3];
        const uint32_t lt = v0 + v1 + v2 + v3;
        uint32_t x = lt;
#pragma unroll
        for (int off = 1; off < 64; off <<= 1) {
            const uint32_t y = __shfl_up(x, off);
            if (lane >= off) x += y;
        }
        const uint32_t ex = x - lt;
        excl[4*tid] = ex; excl[4*tid+1] = ex + v0;
        excl[4*tid+2] = ex + v0 + v1; excl[4*tid+3] = ex + v0 + v1 + v2;
        if (tid == 63) *sTot = x;
    }
    __syncthreads();
    {
        const uint32_t total = *sTot, lim = total - target;
        const uint32_t pe = excl[tid];
        const uint32_t pe1 = (tid == 255) ? total : excl[tid + 1];
        if (pe <= lim && pe1 > lim) {
            *sBin = (uint32_t)tid;
            *sKrem = target - (total - pe1);
            if (wantE) *sE = pe1 - pe;
        }
    }
    __syncthreads();
}

// ---------- K2: per-batch radix select ----------
__global__ __launch_bounds__(256) void selfin_k(const float* __restrict__ scores,
                                                const float* __restrict__ ctrs,
                                                uint32_t* __restrict__ ws) {
    const int b = blockIdx.x, tid = threadIdx.x, w = tid >> 6, lane = tid & 63;
    __shared__ uint32_t list[LIST_CAP];
    __shared__ uint32_t h4[4][257];
    __shared__ uint32_t hist[256], excl[256];
    __shared__ uint32_t scnt[SLICES], soff[SLICES];
    __shared__ uint32_t wcnt[4];
    __shared__ uint32_t sBin, sKrem, sE, sTot, sIstar, sRun, sSpec, sUni, lcnt;
    const float* sc = scores + (size_t)b * NPTS;
    if (tid < SLICES) scnt[tid] = ws[CNT_OFF + b * SLICES + tid];
    __syncthreads();
    if (tid == 0) {
        uint32_t tot = 0; bool ok = true;
        for (int s = 0; s < SLICES; ++s) {
            soff[s] = tot;
            const uint32_t c = scnt[s];
            if (c > SCAP) ok = false;
            tot += c;
        }
        sTot = tot;
        sSpec = (ok && tot >= KTOP && tot <= LIST_CAP) ? 1u : 0u;
        sKrem = KTOP; sIstar = NPTS; lcnt = 0; sUni = 1u;
    }
    __syncthreads();
    uint32_t cnt, prefix = 0u;
    int shift0;
    if (sSpec) {
        cnt = sTot;
#pragma unroll 2
        for (int s = 0; s < SLICES; ++s) {
            const uint32_t c = scnt[s], o = soff[s];
            const uint32_t* src = ws + CAND_OFF + ((size_t)(b * SLICES + s)) * SCAP;
            for (uint32_t i = tid; i < c; i += 256) list[o + i] = src[i];
        }
        __syncthreads();
        const uint32_t b0 = list[0] >> 24;
        bool uni = true;
        for (uint32_t i = tid; i < cnt; i += 256) uni &= ((list[i] >> 24) == b0);
        if (!uni) atomicAnd(&sUni, 0u);
        __syncthreads();
        if (sUni) { prefix = b0 << 24; shift0 = 16; }
        else      { prefix = 0u;       shift0 = 24; }
    } else {
        for (int i = tid; i < 4 * 257; i += 256) (&h4[0][0])[i] = 0;
        __syncthreads();
        const float4* sc4 = reinterpret_cast<const float4*>(sc);
        for (int i4 = tid; i4 < NPTS / 4; i4 += 256) {
            const float4 v = sc4[i4];
            atomicAdd(&h4[w][fmap(v.x) >> 24], 1u);
            atomicAdd(&h4[w][fmap(v.y) >> 24], 1u);
            atomicAdd(&h4[w][fmap(v.z) >> 24], 1u);
            atomicAdd(&h4[w][fmap(v.w) >> 24], 1u);
        }
        __syncthreads();
        hist[tid] = h4[0][tid] + h4[1][tid] + h4[2][tid] + h4[3][tid];
        pick256(hist, excl, tid, lane, KTOP, &sBin, &sKrem, &sE, &sTot, 0);
        const uint32_t beta = sBin;
        for (int i4 = tid; i4 < NPTS / 4; i4 += 256) {
            const float4 v = sc4[i4];
            const uint32_t u[4] = {fmap(v.x), fmap(v.y), fmap(v.z), fmap(v.w)};
#pragma unroll
            for (int j = 0; j < 4; ++j) {
                if ((u[j] >> 24) == beta) {
                    const uint32_t pos = atomicAdd(&lcnt, 1u);
                    if (pos < LIST_CAP) list[pos] = u[j];
                }
            }
        }
        __syncthreads();
        cnt = lcnt < LIST_CAP ? lcnt : LIST_CAP;
        prefix = beta << 24; shift0 = 16;
    }
#pragma unroll 1
    for (int shift = shift0; shift >= 0; shift -= 8) {
        for (int i = tid; i < 4 * 257; i += 256) (&h4[0][0])[i] = 0;
        __syncthreads();
        const uint32_t hi8 = (shift < 24) ? (prefix >> (shift + 8)) : 0u;
        uint32_t* mh = h4[lane & 3];
        for (uint32_t i = tid; i < cnt; i += 256) {
            const uint32_t uu = list[i];
            const bool m = (shift == 24) || ((uu >> (shift + 8)) == hi8);
            if (m) atomicAdd(&mh[(uu >> shift) & 255u], 1u);
        }
        __syncthreads();
        hist[tid] = h4[0][tid] + h4[1][tid] + h4[2][tid] + h4[3][tid];
        const uint32_t target = sKrem;
        pick256(hist, excl, tid, lane, target, &sBin, &sKrem, &sE, &sTot, shift == 0 ? 1 : 0);
        prefix |= sBin << shift;
    }
    const uint32_t R = sKrem, E = sE;
    const uint32_t tbits = (prefix & 0x80000000u) ? (prefix & 0x7fffffffu) : ~prefix;
    if (E != R) {
        const float T = __uint_as_float(tbits);
        if (tid == 0) sRun = 0;
        __syncthreads();
        for (int base = 0; base < NPTS; base += 256) {
            const uint32_t r0 = sRun;
            if (r0 > R) break;
            const int i = base + tid;
            const bool eq = (i < NPTS) && (sc[i] == T);
            const unsigned long long mask = __ballot(eq);
            if (lane == 0) wcnt[w] = (uint32_t)__popcll(mask);
            __syncthreads();
            uint32_t before = 0, total = 0;
#pragma unroll
            for (int ww = 0; ww < 4; ++ww) {
                const uint32_t c = wcnt[ww];
                if (ww < w) before += c;
                total += c;
            }
            if (eq) {
                const uint32_t rank = r0 + before + (uint32_t)__popcll(mask & ((1ull << lane) - 1ull));
                if (rank == R) sIstar = (uint32_t)i;
            }
            __syncthreads();
            if (tid == 0) sRun = r0 + total;
            __syncthreads();
        }
        __syncthreads();
    }
    if (tid == 0) {
        ws[STATE_OFF + b * 2] = tbits;
        ws[STATE_OFF + b * 2 + 1] = sIstar;
    }
}

// ---------- exact (numpy-bit-identical) gt check for one point ----------
__device__ __noinline__ bool exact_gt(float px, float py, float pz,
                                      const float* __restrict__ C) {
    bool hit = false;
#pragma unroll 1
    for (int k = 0; k < NBOX; ++k) {
        float dx = px - C[3 * k + 0];
        float dy = py - C[3 * k + 1];
        float dz = pz - C[3 * k + 2];
        float d2 = __fadd_rn(__fadd_rn(__fmul_rn(dx, dx), __fmul_rn(dy, dy)),
                             __fmul_rn(dz, dz));
        if (__fsqrt_rn(d2) < THRF) hit = true;
    }
    return hit;
}

// ---------- K3: body, 8 pts/thread, LDS-staged boxes, NO pointer-aliased locals ----------
#define PPT 8
__global__ __launch_bounds__(256) void main_k(const float* __restrict__ scores,
                                              const float* __restrict__ points,
                                              const float* __restrict__ ctrs,
                                              const uint32_t* __restrict__ ws,
                                              float* __restrict__ out) {
    __shared__ float4 sbox[NBOX];  // (-2cx,-2cy,-2cz, c.c); 1 KB
    const int b = blockIdx.y, tid = threadIdx.x;
    const float* __restrict__ C = ctrs + (size_t)b * NBOX * 3;
    if (tid < NBOX) {
        const float cx = C[3 * tid], cy = C[3 * tid + 1], cz = C[3 * tid + 2];
        sbox[tid] = make_float4(-2.0f * cx, -2.0f * cy, -2.0f * cz,
                                fmaf(cx, cx, fmaf(cy, cy, cz * cz)));
    }
    __syncthreads();

    const int i0 = (blockIdx.x * 256 + tid) * PPT;
    if (i0 >= NPTS) return;  // NPTS % 8 == 0: threads fully valid or fully invalid

    const float T = __uint_as_float(ws[STATE_OFF + b * 2]);
    const uint32_t Istar = ws[STATE_OFF + b * 2 + 1];

    // 8 points = 24 floats = 6 float4 (i0*3 % 4 == 0). Unpack via named components.
    const float4* P4 = reinterpret_cast<const float4*>(points + ((size_t)b * NPTS + i0) * 3);
    const float4 q0 = P4[0], q1 = P4[1], q2 = P4[2], q3 = P4[3], q4 = P4[4], q5 = P4[5];
    float px[PPT], py[PPT], pz[PPT];
    px[0] = q0.x; py[0] = q0.y; pz[0] = q0.z;
    px[1] = q0.w; py[1] = q1.x; pz[1] = q1.y;
    px[2] = q1.z; py[2] = q1.w; pz[2] = q2.x;
    px[3] = q2.y; py[3] = q2.z; pz[3] = q2.w;
    px[4] = q3.x; py[4] = q3.y; pz[4] = q3.z;
    px[5] = q3.w; py[5] = q4.x; pz[5] = q4.y;
    px[6] = q4.z; py[6] = q4.w; pz[6] = q5.x;
    px[7] = q5.y; py[7] = q5.z; pz[7] = q5.w;

    float m2[PPT];
#pragma unroll
    for (int j = 0; j < PPT; ++j) m2[j] = 1e30f;

    // 64 boxes x 8 points: 4 VALU per box-point, broadcast ds_read_b128 per box
#pragma unroll 8
    for (int k = 0; k < NBOX; ++k) {
        const float4 B = sbox[k];
#pragma unroll
        for (int j = 0; j < PPT; ++j) {
            const float t = fmaf(B.x, px[j], fmaf(B.y, py[j], fmaf(B.z, pz[j], B.w)));
            m2[j] = fminf(m2[j], t);
        }
    }

    const float4* S4 = reinterpret_cast<const float4*>(scores + (size_t)b * NPTS + i0);
    const float4 sv0 = S4[0], sv1 = S4[1];
    float s[PPT];
    s[0] = sv0.x; s[1] = sv0.y; s[2] = sv0.z; s[3] = sv0.w;
    s[4] = sv1.x; s[5] = sv1.y; s[6] = sv1.z; s[7] = sv1.w;

    float pr[PPT], ls[PPT];
#pragma unroll
    for (int j = 0; j < PPT; ++j) {
        const float pp = fmaf(px[j], px[j], fmaf(py[j], py[j], pz[j] * pz[j]));
        const float m = pp + m2[j];
        bool gt;
        if (m < C_LO) gt = true;
        else if (m >= C_HI) gt = false;
        else gt = exact_gt(px[j], py[j], pz[j], C);  // rare boundary band
        const bool sm = (s[j] > T) || (s[j] == T && (uint32_t)(i0 + j) < Istar);
        pr[j] = (gt || sm) ? 1.0f : 0.0f;
        const float x = gt ? -s[j] : s[j];
        // fast softplus: tolerance is bf16-level (9.4e-2); hw exp/log err ~1e-6
        ls[j] = fmaxf(x, 0.0f) + __logf(1.0f + __expf(-fabsf(s[j])));
    }
    float4* o0 = reinterpret_cast<float4*>(out + (size_t)b * NPTS + i0);
    float4* o1 = reinterpret_cast<float4*>(out + (size_t)BB * NPTS + (size_t)b * NPTS + i0);
    o0[0] = make_float4(pr[0], pr[1], pr[2], pr[3]);
    o0[1] = make_float4(pr[4], pr[5], pr[6], pr[7]);
    o1[0] = make_float4(ls[0], ls[1], ls[2], ls[3]);
    o1[1] = make_float4(ls[4], ls[5], ls[6], ls[7]);
}

extern "C" void kernel_launch(void* const* d_in, const int* in_sizes, int n_in,
                              void* d_out, int out_size, void* d_ws, size_t ws_size,
                              hipStream_t stream) {
    const float* scores = (const float*)d_in[0];
    const float* points = (const float*)d_in[1];
    const float* ctrs   = (const float*)d_in[2];
    float* out = (float*)d_out;
    uint32_t* ws = (uint32_t*)d_ws;

    const dim3 gridC(SLICES, BB);   // 256 blocks
    cand_k<<<gridC, 256, 0, stream>>>(scores, ws);
    selfin_k<<<BB, 256, 0, stream>>>(scores, ctrs, ws);
    const dim3 gridP((NPTS / PPT + 255) / 256, BB);  // 49 x 16
    main_k<<<gridP, 256, 0, stream>>>(scores, points, ctrs, ws, out);
}